// Round 3
// baseline (90.818 us; speedup 1.0000x reference)
//
#include <hip/hip_runtime.h>
#include <math.h>
#include <stdint.h>

// Problem: bsz=16, sent_len=512 -> N=8192 rows, D=768, P=20, fp32 io.
// cos[n][p] = <rm,w2[p]> / (max(sqrt(<rr,w2[p]>),eps)*max(sqrt(<mm,w2[p]>),eps))
//
// v4: zero-staging design. A has no cross-thread reuse -> global->VGPR (as v3).
// W^2 is 60 KB, L2-resident, reused by all 512 blocks -> ALSO global->VGPR,
// squared + bf16-converted in-register (same values as the old LDS staging).
// LDS holds ONLY the 48 KB epilogue scratch; ONE __syncthreads() total.
// K split 8 ways (96/wave = 3 MFMA slices): per-wave chain = issue 24 loads,
// one wait, 3 short pack+MFMA slices. 512 blocks x 8 waves, VGPR<=128 via
// __launch_bounds__(512,4) -> 2 blocks/CU, 16 waves/CU, ONE generation.

static constexpr int D_DIM   = 768;
static constexpr int NP      = 20;
static constexpr int NROWS   = 8192;
static constexpr int ROWS_PB = 16;                 // M-tile per block
static constexpr int BLOCKS  = NROWS / ROWS_PB;    // 512
static constexpr int NTHR    = 512;                // 8 waves
static constexpr int NW      = 8;
static constexpr int KW      = D_DIM / NW;         // 96 = split-K per wave
static constexpr int KSLICE  = 32;
static constexpr int NSLICES = KW / KSLICE;        // 3

typedef short  short8  __attribute__((ext_vector_type(8)));   // 8 bf16
typedef float  float4v __attribute__((ext_vector_type(4)));   // MFMA C/D

__device__ __forceinline__ unsigned short bf16_rne(float x) {
  unsigned u = __float_as_uint(x);
  u += 0x7FFFu + ((u >> 16) & 1u);
  return (unsigned short)(u >> 16);
}
__device__ __forceinline__ float bf16f(unsigned short h) {
  return __uint_as_float(((unsigned)h) << 16);
}

__global__ __launch_bounds__(NTHR, 4) void atte_cos_v4(
    const float* __restrict__ repres,
    const float* __restrict__ max_att,
    const float* __restrict__ weight,
    float* __restrict__ out)
{
  const int tid  = threadIdx.x;
  const int wave = tid >> 6;
  const int lane = tid & 63;
  const int row0 = blockIdx.x * ROWS_PB;
  const int k0   = wave * KW;        // this wave's K range
  const int part = lane >> 4;        // k-offset part*8 within MFMA frags
  const int mrow = lane & 15;        // A row within tile

  // Epilogue scratch only: [q*2+ct][wave][lane] float4 = 6*8*64*16 B.
  __shared__ __align__(16) char smem[6 * NW * 64 * 16];   // 49152

  // ---- A fragment bases: row (row0+mrow), k = k0 + part*8. One slice's wave
  // footprint = 16 rows x 128 B contiguous each (cache-line coalesced).
  const float* ar = repres  + (size_t)(row0 + mrow) * D_DIM + k0 + part * 8;
  const float* am = max_att + (size_t)(row0 + mrow) * D_DIM + k0 + part * 8;

  // ---- W fragment bases: col = lane&15 (ctile 0) / 16+(lane&15) clamped
  // (ctile 1; cols 20..31 duplicate col 19, junk results never stored).
  const int cA = lane & 15;
  const int cB = min(16 + (lane & 15), NP - 1);
  const float* wA = weight + (size_t)cA * D_DIM + k0 + part * 8;
  const float* wB = weight + (size_t)cB * D_DIM + k0 + part * 8;

  // Issue ALL loads up front (24 float4/lane in flight; in-order issue means
  // the W-convert's wait covers the A loads too). No barriers, no LDS staging.
  float4 fr[NSLICES][2], fm[NSLICES][2];
#pragma unroll
  for (int s = 0; s < NSLICES; ++s) {
    fr[s][0] = *(const float4*)(ar + s * KSLICE);
    fr[s][1] = *(const float4*)(ar + s * KSLICE + 4);
    fm[s][0] = *(const float4*)(am + s * KSLICE);
    fm[s][1] = *(const float4*)(am + s * KSLICE + 4);
  }
  float4 fwA[NSLICES][2], fwB[NSLICES][2];
#pragma unroll
  for (int s = 0; s < NSLICES; ++s) {
    fwA[s][0] = *(const float4*)(wA + s * KSLICE);
    fwA[s][1] = *(const float4*)(wA + s * KSLICE + 4);
    fwB[s][0] = *(const float4*)(wB + s * KSLICE);
    fwB[s][1] = *(const float4*)(wB + s * KSLICE + 4);
  }

  // w^2 -> bf16 in-register (identical rounding to the old LDS-staged path).
  short8 bh0[NSLICES], bh1[NSLICES];
#pragma unroll
  for (int s = 0; s < NSLICES; ++s) {
    float wa[8], wb[8];
    *(float4*)&wa[0] = fwA[s][0]; *(float4*)&wa[4] = fwA[s][1];
    *(float4*)&wb[0] = fwB[s][0]; *(float4*)&wb[4] = fwB[s][1];
#pragma unroll
    for (int j = 0; j < 8; ++j) {
      bh0[s][j] = (short)bf16_rne(wa[j] * wa[j]);
      bh1[s][j] = (short)bf16_rne(wb[j] * wb[j]);
    }
  }

  float4v acc[6] = {};   // [q*2 + ct]; q: 0=dot 1=||rw||^2 2=||mw||^2

#pragma unroll
  for (int s = 0; s < NSLICES; ++s) {
    float rv[8], mv[8];
    *(float4*)&rv[0] = fr[s][0];
    *(float4*)&rv[4] = fr[s][1];
    *(float4*)&mv[0] = fm[s][0];
    *(float4*)&mv[4] = fm[s][1];

    // Products fp32; dot gets hi+lo bf16 split (err 2^-17), norms hi-only.
    short8 a0h, a0l, a1h, a2h;
#pragma unroll
    for (int j = 0; j < 8; ++j) {
      const float pm = rv[j] * mv[j];
      const float pr = rv[j] * rv[j];
      const float pq = mv[j] * mv[j];
      const unsigned short h = bf16_rne(pm);
      a0h[j] = (short)h;
      a0l[j] = (short)bf16_rne(pm - bf16f(h));
      a1h[j] = (short)bf16_rne(pr);
      a2h[j] = (short)bf16_rne(pq);
    }

    const short8 b0 = bh0[s];
    const short8 b1 = bh1[s];

    acc[0] = __builtin_amdgcn_mfma_f32_16x16x32_bf16(a0h, b0, acc[0], 0, 0, 0);
    acc[0] = __builtin_amdgcn_mfma_f32_16x16x32_bf16(a0l, b0, acc[0], 0, 0, 0);
    acc[1] = __builtin_amdgcn_mfma_f32_16x16x32_bf16(a0h, b1, acc[1], 0, 0, 0);
    acc[1] = __builtin_amdgcn_mfma_f32_16x16x32_bf16(a0l, b1, acc[1], 0, 0, 0);
    acc[2] = __builtin_amdgcn_mfma_f32_16x16x32_bf16(a1h, b0, acc[2], 0, 0, 0);
    acc[3] = __builtin_amdgcn_mfma_f32_16x16x32_bf16(a1h, b1, acc[3], 0, 0, 0);
    acc[4] = __builtin_amdgcn_mfma_f32_16x16x32_bf16(a2h, b0, acc[4], 0, 0, 0);
    acc[5] = __builtin_amdgcn_mfma_f32_16x16x32_bf16(a2h, b1, acc[5], 0, 0, 0);
  }

  // ---- cross-wave K reduction over 8 waves (first and only LDS use).
#pragma unroll
  for (int qc = 0; qc < 6; ++qc)
    *(float4v*)(smem + ((qc * NW + wave) * 64 + lane) * 16) = acc[qc];
  __syncthreads();

  if (wave < 2) {              // wave = column-tile; same (row,col)->lane map
    const int ct = wave;
    float4v c0 = {}, c1 = {}, c2 = {};
#pragma unroll
    for (int wv = 0; wv < NW; ++wv) {
      c0 += *(const float4v*)(smem + (((0 * 2 + ct) * NW + wv) * 64 + lane) * 16);
      c1 += *(const float4v*)(smem + (((1 * 2 + ct) * NW + wv) * 64 + lane) * 16);
      c2 += *(const float4v*)(smem + (((2 * 2 + ct) * NW + wv) * 64 + lane) * 16);
    }
    const int col = ct * 16 + (lane & 15);
    if (col < NP) {
      const int rbase = row0 + (lane >> 4) * 4;   // C row = (lane>>4)*4 + reg
#pragma unroll
      for (int r = 0; r < 4; ++r) {
        const float n1 = fmaxf(sqrtf(c1[r]), 1e-8f);
        const float n2 = fmaxf(sqrtf(c2[r]), 1e-8f);
        out[(size_t)(rbase + r) * NP + col] = c0[r] / (n1 * n2);
      }
    }
  }
}

extern "C" void kernel_launch(void* const* d_in, const int* in_sizes, int n_in,
                              void* d_out, int out_size, void* d_ws, size_t ws_size,
                              hipStream_t stream) {
  atte_cos_v4<<<BLOCKS, NTHR, 0, stream>>>(
      (const float*)d_in[0], (const float*)d_in[1],
      (const float*)d_in[2], (float*)d_out);
}

// Round 4
// 89.025 us; speedup vs baseline: 1.0201x; 1.0201x over previous
//
#include <hip/hip_runtime.h>
#include <math.h>
#include <stdint.h>

// Problem constants: bsz=16, sent_len=512 -> N=8192 rows, D=768, P=20. fp32 io.
static constexpr int D_DIM   = 768;
static constexpr int NP      = 20;
static constexpr int NROWS   = 8192;
static constexpr int ROWS_PB = 16;                 // M-tile per block
static constexpr int BLOCKS  = NROWS / ROWS_PB;    // 512 (2 blocks/CU, one generation)
static constexpr int KW      = 192;                // split-K: k-range per wave
static constexpr int KSLICE  = 32;                 // one MFMA k-step per slice
static constexpr int NSLICES = KW / KSLICE;        // 6

typedef short  short8  __attribute__((ext_vector_type(8)));   // 8 bf16 (4 VGPRs)
typedef float  float4v __attribute__((ext_vector_type(4)));   // MFMA C/D

// ---- LDS map (bytes). A: wave-private double-buffered slices. B: w^2 bf16. ----
static constexpr int A_WAVE = 8192;     // per wave: 2 bufs x (r 2048 + m 2048)
static constexpr int A_BUF  = 4096;
static constexpr int A_MAT  = 2048;     // 16 rows x 32 floats
static constexpr int B_OFF  = 32768;
static constexpr int B_CSTR = 776 * 2;  // col stride: 768 + 8 pad bf16 (4-way-free banks)
static constexpr int LDS_SZ = B_OFF + NP * B_CSTR;  // 63808 < 64K -> 2 blocks/CU

// Async global->LDS DMA, 16 B/lane (dest = wave-uniform base + lane*16).
__device__ __forceinline__ void async_copy16(const void* g, void* l) {
  __builtin_amdgcn_global_load_lds(
      (const __attribute__((address_space(1))) unsigned int*)(uintptr_t)g,
      (__attribute__((address_space(3))) unsigned int*)(uint32_t)(uintptr_t)l,
      16, 0, 0);
}

__device__ __forceinline__ unsigned short bf16_rne(float x) {
  unsigned u = __float_as_uint(x);
  u += 0x7FFFu + ((u >> 16) & 1u);
  return (unsigned short)(u >> 16);
}
__device__ __forceinline__ float bf16f(unsigned short h) {
  return __uint_as_float(((unsigned)h) << 16);
}

__global__ __launch_bounds__(256) void atte_cos_mfma(
    const float* __restrict__ repres,
    const float* __restrict__ max_att,
    const float* __restrict__ weight,
    float* __restrict__ out)
{
  const int tid  = threadIdx.x;
  const int wave = tid >> 6;
  const int lane = tid & 63;
  const int row0 = blockIdx.x * ROWS_PB;
  const int k0   = wave * KW;          // this wave's K range
  const int part = lane >> 4;          // 0..3 -> k-offset part*8 in MFMA frags
  const int mrow = lane & 15;          // A row within tile / C col index

  __shared__ __align__(16) char smem[LDS_SZ];
  char* a_base = smem + wave * A_WAVE;

  // Stage slice s (32 k) of this wave's range into buffer b. Rows are stored
  // 128 B each with 16-B granules rotated by 2*(row&3) so that A-fragment
  // reads (16 rows, stride 128 B) hit 4 bank groups instead of 1 (16-way->4-way).
  // Global side of the DMA is an arbitrary per-lane gather; LDS side is
  // lane-contiguous as required.
  auto stage = [&](int s, int b) {
#pragma unroll
    for (int j = 0; j < 2; ++j) {
      const int slot = j * 64 + lane;          // 0..127 = row*8 + granule
      const int row  = slot >> 3;
      const int gp   = slot & 7;               // physical granule in row
      const int gl   = (gp - 2 * (row & 3)) & 7;  // logical granule (unrotate)
      const float* gr = repres  + (size_t)(row0 + row) * D_DIM + k0 + s * KSLICE + gl * 4;
      const float* gm = max_att + (size_t)(row0 + row) * D_DIM + k0 + s * KSLICE + gl * 4;
      char* la = a_base + b * A_BUF + slot * 16;
      async_copy16(gr, la);
      async_copy16(gm, la + A_MAT);
    }
  };

  stage(0, 0);
  stage(1, 1);

  // B staging: w^2 -> bf16, layout [col][k] with padded stride (shared by all
  // waves; one-time). 768 = 3*256 so k = j*256+tid needs no div.
  for (int col = 0; col < NP; ++col) {
#pragma unroll
    for (int j = 0; j < 3; ++j) {
      const int k = j * 256 + tid;
      const float wv = weight[col * D_DIM + k];
      *(unsigned short*)(smem + B_OFF + col * B_CSTR + k * 2) = bf16_rne(wv * wv);
    }
  }

  __syncthreads();  // B visible to all waves; also drains slices 0,1 (vmcnt 0)

  // A-fragment read offset: row mrow, logical floats part*8..+7 -> physical
  // offset rotated by 8*(mrow&3) floats (granule-aligned, never wraps).
  const int a_off = mrow * 128 + (((part + (mrow & 3)) & 3) * 32);
  // B fragments: B[k0+s*32+part*8 + j][col], contiguous 16 B along k.
  const char* b0p = smem + B_OFF + (lane & 15) * B_CSTR + (k0 + part * 8) * 2;
  const int c1col = min(16 + (lane & 15), NP - 1);   // cols 20..31: junk, unstored
  const char* b1p = smem + B_OFF + c1col * B_CSTR + (k0 + part * 8) * 2;

  float4v acc[6] = {};  // [q*2 + ct]; q: 0=dot 1=||rw||^2 2=||mw||^2

#pragma unroll
  for (int s = 0; s < NSLICES; ++s) {
    // Slice s's 4 DMAs done (<=4 outstanding = prefetch of s+1 stays in flight).
    __builtin_amdgcn_s_waitcnt(0x0F74);  // vmcnt(4), exp/lgkm no-wait
    const char* ab = a_base + (s & 1) * A_BUF;

    float rv[8], mv[8];
    *(float4*)&rv[0] = *(const float4*)(ab + a_off);
    *(float4*)&rv[4] = *(const float4*)(ab + a_off + 16);
    *(float4*)&mv[0] = *(const float4*)(ab + A_MAT + a_off);
    *(float4*)&mv[4] = *(const float4*)(ab + A_MAT + a_off + 16);

    // Products in fp32; dot gets hi+lo bf16 split (error 2^-17), norms hi-only
    // (positive terms -> bf16 noise averages to ~1e-5 relative).
    short8 a0h, a0l, a1h, a2h;
#pragma unroll
    for (int j = 0; j < 8; ++j) {
      const float pm = rv[j] * mv[j];
      const float pr = rv[j] * rv[j];
      const float pq = mv[j] * mv[j];
      const unsigned short h = bf16_rne(pm);
      a0h[j] = (short)h;
      a0l[j] = (short)bf16_rne(pm - bf16f(h));
      a1h[j] = (short)bf16_rne(pr);
      a2h[j] = (short)bf16_rne(pq);
    }

    const short8 b0 = *(const short8*)(b0p + s * 64);
    const short8 b1 = *(const short8*)(b1p + s * 64);

    acc[0] = __builtin_amdgcn_mfma_f32_16x16x32_bf16(a0h, b0, acc[0], 0, 0, 0);
    acc[0] = __builtin_amdgcn_mfma_f32_16x16x32_bf16(a0l, b0, acc[0], 0, 0, 0);
    acc[1] = __builtin_amdgcn_mfma_f32_16x16x32_bf16(a0h, b1, acc[1], 0, 0, 0);
    acc[1] = __builtin_amdgcn_mfma_f32_16x16x32_bf16(a0l, b1, acc[1], 0, 0, 0);
    acc[2] = __builtin_amdgcn_mfma_f32_16x16x32_bf16(a1h, b0, acc[2], 0, 0, 0);
    acc[3] = __builtin_amdgcn_mfma_f32_16x16x32_bf16(a1h, b1, acc[3], 0, 0, 0);
    acc[4] = __builtin_amdgcn_mfma_f32_16x16x32_bf16(a2h, b0, acc[4], 0, 0, 0);
    acc[5] = __builtin_amdgcn_mfma_f32_16x16x32_bf16(a2h, b1, acc[5], 0, 0, 0);

    if (s + 2 < NSLICES) {
      // Drain our ds_reads before the DMA overwrites this buffer.
      __builtin_amdgcn_s_waitcnt(0xC07F);  // lgkmcnt(0), vm no-wait
      stage(s + 2, s & 1);
    }
  }

  // ---- cross-wave K reduction (A region is dead; reuse as scratch) ----
  __syncthreads();  // all waves done computing before anyone scribbles scratch
#pragma unroll
  for (int qc = 0; qc < 6; ++qc)
    *(float4v*)(smem + ((qc * 4 + wave) * 64 + lane) * 16) = acc[qc];
  __syncthreads();

  if (wave < 2) {                // wave = column-tile; same (row,col)->lane map
    const int ct = wave;
    float4v c0 = {}, c1 = {}, c2 = {};
#pragma unroll
    for (int wv = 0; wv < 4; ++wv) {
      c0 += *(const float4v*)(smem + (((0 * 2 + ct) * 4 + wv) * 64 + lane) * 16);
      c1 += *(const float4v*)(smem + (((1 * 2 + ct) * 4 + wv) * 64 + lane) * 16);
      c2 += *(const float4v*)(smem + (((2 * 2 + ct) * 4 + wv) * 64 + lane) * 16);
    }
    const int col = ct * 16 + (lane & 15);
    if (col < NP) {
      const int rbase = row0 + (lane >> 4) * 4;  // C row = (lane>>4)*4 + reg
#pragma unroll
      for (int r = 0; r < 4; ++r) {
        const float n1 = fmaxf(sqrtf(c1[r]), 1e-8f);
        const float n2 = fmaxf(sqrtf(c2[r]), 1e-8f);
        out[(size_t)(rbase + r) * NP + col] = c0[r] / (n1 * n2);
      }
    }
  }
}

extern "C" void kernel_launch(void* const* d_in, const int* in_sizes, int n_in,
                              void* d_out, int out_size, void* d_ws, size_t ws_size,
                              hipStream_t stream) {
  const float* repres  = (const float*)d_in[0];
  const float* max_att = (const float*)d_in[1];
  const float* weight  = (const float*)d_in[2];
  float* out = (float*)d_out;

  atte_cos_mfma<<<BLOCKS, 256, 0, stream>>>(repres, max_att, weight, out);
}